// Round 1
// baseline (648.972 us; speedup 1.0000x reference)
//
#include <hip/hip_runtime.h>
#include <cstdint>
#include <cstddef>

// Problem constants (B=2, S=1024, H=1024, E=8, K=2, F=4096)
#define T_TOK 2048
#define H_DIM 1024
#define E_NUM 8
#define F_DIM 4096
#define NG 9          // 8 experts + 1 shared
#define RTOT 6144     // 2048*2 expert rows + 2048 shared rows

typedef unsigned short ushort_t;
typedef __attribute__((ext_vector_type(8))) short bf16x8;
typedef __attribute__((ext_vector_type(4))) float f32x4;

// ---- workspace layout (bytes) ----
constexpr size_t OFF_TTI = 0;               // int[4096]   top-2 expert idx per token
constexpr size_t OFF_TTW = 16u << 10;       // float[4096] top-2 weights per token
constexpr size_t OFF_CNT = 32u << 10;       // int[16]     per-group row counts
constexpr size_t OFF_OFFS = (32u << 10) + 256; // int[16]  per-group packed offsets
constexpr size_t OFF_RID = 64u << 10;       // int[6144]   token<<2 | slot
constexpr size_t OFF_WTS = 96u << 10;       // float[6144] combine weight per packed row
constexpr size_t OFF_XBF = 1u << 20;        // bf16 x      [2048][1024]   (4MB)
constexpr size_t OFF_WUB = 8u << 20;        // bf16 Wu     [9][4096][1024] (72MB)
constexpr size_t OFF_WDB = 80u << 20;       // bf16 Wd     [9][1024][4096] (72MB)
constexpr size_t OFF_A   = 152u << 20;      // bf16 act    [6144][4096]   (48MB)
constexpr size_t OFF_Y   = 200u << 20;      // f32 Y       [2048][3][1024] (24MB)
// total 224MB

__device__ __forceinline__ ushort_t f2bf(float f) {
  union { float f; unsigned u; } v; v.f = f;
  unsigned r = v.u + 0x7FFFu + ((v.u >> 16) & 1u);
  return (ushort_t)(r >> 16);
}

__device__ __forceinline__ float gelu_exact(float v) {
  return 0.5f * v * (1.0f + erff(v * 0.70710678118654752f));
}

// ---------------- 1. routing: one wave per token ----------------
__global__ __launch_bounds__(256) void route_k(const float* __restrict__ x,
                                               const float* __restrict__ gw,
                                               const float* __restrict__ gb,
                                               int* __restrict__ tt_idx,
                                               float* __restrict__ tt_w) {
  const int lane = threadIdx.x & 63;
  const int wid = threadIdx.x >> 6;
  const int t = blockIdx.x * 4 + wid;
  if (t >= T_TOK) return;
  const float* xr = x + (size_t)t * H_DIM;
  float acc[8] = {0.f, 0.f, 0.f, 0.f, 0.f, 0.f, 0.f, 0.f};
  for (int i = 0; i < H_DIM; i += 64) {
    const int k = i + lane;
    const float xv = xr[k];
#pragma unroll
    for (int e = 0; e < 8; ++e) acc[e] = fmaf(xv, gw[e * H_DIM + k], acc[e]);
  }
#pragma unroll
  for (int e = 0; e < 8; ++e) {
    float v = acc[e];
#pragma unroll
    for (int s = 32; s; s >>= 1) v += __shfl_xor(v, s, 64);
    acc[e] = v;
  }
  if (lane == 0) {
    float sc[8];
#pragma unroll
    for (int e = 0; e < 8; ++e) sc[e] = 1.0f / (1.0f + expf(-(acc[e] + gb[e])));
    int i0 = 0;
#pragma unroll
    for (int e = 1; e < 8; ++e) if (sc[e] > sc[i0]) i0 = e;
    int i1 = (i0 == 0) ? 1 : 0;
#pragma unroll
    for (int e = 0; e < 8; ++e) if (e != i0 && sc[e] > sc[i1]) i1 = e;
    const float d = sc[i0] + sc[i1] + 1e-6f;
    tt_idx[2 * t] = i0;
    tt_idx[2 * t + 1] = i1;
    tt_w[2 * t] = sc[i0] / d;
    tt_w[2 * t + 1] = sc[i1] / d;
  }
}

// ---------------- 2. build packed per-expert lists ----------------
__global__ __launch_bounds__(256) void build_k(const int* __restrict__ tt_idx,
                                               const float* __restrict__ tt_w,
                                               int* __restrict__ counts,
                                               int* __restrict__ offs,
                                               int* __restrict__ rid,
                                               float* __restrict__ wts) {
  __shared__ int cnt[NG];
  __shared__ int cur[NG];
  const int tid = threadIdx.x;
  if (tid < NG) cnt[tid] = 0;
  __syncthreads();
  for (int p = tid; p < 2 * T_TOK; p += 256) atomicAdd(&cnt[tt_idx[p]], 1);
  __syncthreads();
  if (tid == 0) {
    int run = 0;
    for (int e = 0; e < E_NUM; ++e) {
      offs[e] = run;
      counts[e] = cnt[e];
      cur[e] = run;
      run += cnt[e];
    }
    offs[E_NUM] = 2 * T_TOK;   // == 4096 always
    counts[E_NUM] = T_TOK;
    cur[E_NUM] = 2 * T_TOK;
  }
  __syncthreads();
  for (int p = tid; p < 2 * T_TOK; p += 256) {
    const int e = tt_idx[p];
    const int pos = atomicAdd(&cur[e], 1);
    rid[pos] = ((p >> 1) << 2) | (p & 1);
    wts[pos] = tt_w[p];
  }
  for (int p = tid; p < T_TOK; p += 256) {
    rid[2 * T_TOK + p] = (p << 2) | 2;
    wts[2 * T_TOK + p] = 0.1f;
  }
}

// ---------------- 3. f32 -> bf16 conversion of weights + x ----------------
__global__ __launch_bounds__(256) void convert_k(const float* __restrict__ Wu,
                                                 const float* __restrict__ sWu,
                                                 const float* __restrict__ Wd,
                                                 const float* __restrict__ sWd,
                                                 const float* __restrict__ x,
                                                 ushort_t* __restrict__ Wub,
                                                 ushort_t* __restrict__ Wdb,
                                                 ushort_t* __restrict__ Xbf) {
  const long WE = (long)NG * F_DIM * H_DIM;   // 37748736
  const long W8 = (long)8 * F_DIM * H_DIM;    // 33554432
  const long XE = (long)T_TOK * H_DIM;        // 2097152
  const long total = (2 * WE + XE) / 8;
  for (long i = blockIdx.x * 256L + threadIdx.x; i < total; i += (long)gridDim.x * 256L) {
    const long base = i * 8;
    const float* src;
    ushort_t* dst;
    if (base < WE) {
      const long o = base;
      src = (o < W8) ? (Wu + o) : (sWu + (o - W8));
      dst = Wub + o;
    } else if (base < 2 * WE) {
      const long o = base - WE;
      src = (o < W8) ? (Wd + o) : (sWd + (o - W8));
      dst = Wdb + o;
    } else {
      const long o = base - 2 * WE;
      src = x + o;
      dst = Xbf + o;
    }
    const float4 v0 = *(const float4*)src;
    const float4 v1 = *(const float4*)(src + 4);
    bf16x8 r;
    r[0] = (short)f2bf(v0.x); r[1] = (short)f2bf(v0.y);
    r[2] = (short)f2bf(v0.z); r[3] = (short)f2bf(v0.w);
    r[4] = (short)f2bf(v1.x); r[5] = (short)f2bf(v1.y);
    r[6] = (short)f2bf(v1.z); r[7] = (short)f2bf(v1.w);
    *(bf16x8*)dst = r;
  }
}

// ---------------- 4. grouped up-GEMM + bias + GELU + weight scaling ----------------
// C[i][j] = sum_k Xg[i][k] * Wu[g][n0+j][k]; tile 128x128, BK=32
#define LDS_STRIDE 40  // pad 32 -> 40 ushorts: 80B row stride, 2-way bank alias (free)
__global__ __launch_bounds__(256) void up_gemm(const ushort_t* __restrict__ Xbf,
                                               const ushort_t* __restrict__ Wub,
                                               const int* __restrict__ counts,
                                               const int* __restrict__ offs,
                                               const int* __restrict__ rid,
                                               const float* __restrict__ wts,
                                               const float* __restrict__ bu,
                                               const float* __restrict__ sbu,
                                               ushort_t* __restrict__ Aout) {
  const int g = blockIdx.y >> 4;
  const int mt = blockIdx.y & 15;
  const int rows = counts[g];
  if (mt * 128 >= rows) return;
  const int off = offs[g];
  const int n0 = blockIdx.x * 128;

  __shared__ ushort_t lA[128 * LDS_STRIDE];
  __shared__ ushort_t lB[128 * LDS_STRIDE];

  const int tid = threadIdx.x;
  const int lane = tid & 63;
  const int wid = tid >> 6;
  const int rs0 = tid >> 2;        // staging row 0..63
  const int cb = (tid & 3) * 8;    // staging k-offset (elems)

  int ig0 = mt * 128 + rs0;        if (ig0 >= rows) ig0 = rows - 1;
  int ig1 = mt * 128 + rs0 + 64;   if (ig1 >= rows) ig1 = rows - 1;
  const ushort_t* srcA0 = Xbf + (size_t)(rid[off + ig0] >> 2) * H_DIM + cb;
  const ushort_t* srcA1 = Xbf + (size_t)(rid[off + ig1] >> 2) * H_DIM + cb;
  const ushort_t* Wg = Wub + (size_t)g * F_DIM * H_DIM;
  const ushort_t* srcB0 = Wg + (size_t)(n0 + rs0) * H_DIM + cb;
  const ushort_t* srcB1 = srcB0 + (size_t)64 * H_DIM;

  f32x4 acc[4][4];
#pragma unroll
  for (int m = 0; m < 4; ++m)
#pragma unroll
    for (int n = 0; n < 4; ++n) acc[m][n] = (f32x4){0.f, 0.f, 0.f, 0.f};

  const int wr = (wid >> 1) * 64;
  const int wc = (wid & 1) * 64;
  const int fr = lane & 15;
  const int fk = (lane >> 4) * 8;

  for (int k0 = 0; k0 < H_DIM; k0 += 32) {
    const bf16x8 va0 = *(const bf16x8*)(srcA0 + k0);
    const bf16x8 va1 = *(const bf16x8*)(srcA1 + k0);
    const bf16x8 vb0 = *(const bf16x8*)(srcB0 + k0);
    const bf16x8 vb1 = *(const bf16x8*)(srcB1 + k0);
    __syncthreads();
    *(bf16x8*)&lA[rs0 * LDS_STRIDE + cb] = va0;
    *(bf16x8*)&lA[(rs0 + 64) * LDS_STRIDE + cb] = va1;
    *(bf16x8*)&lB[rs0 * LDS_STRIDE + cb] = vb0;
    *(bf16x8*)&lB[(rs0 + 64) * LDS_STRIDE + cb] = vb1;
    __syncthreads();
    bf16x8 af[4], bfr[4];
#pragma unroll
    for (int m = 0; m < 4; ++m) af[m] = *(const bf16x8*)&lA[(wr + m * 16 + fr) * LDS_STRIDE + fk];
#pragma unroll
    for (int n = 0; n < 4; ++n) bfr[n] = *(const bf16x8*)&lB[(wc + n * 16 + fr) * LDS_STRIDE + fk];
#pragma unroll
    for (int m = 0; m < 4; ++m)
#pragma unroll
      for (int n = 0; n < 4; ++n)
        acc[m][n] = __builtin_amdgcn_mfma_f32_16x16x32_bf16(af[m], bfr[n], acc[m][n], 0, 0, 0);
  }

  const float* bug = (g < E_NUM) ? (bu + (size_t)g * F_DIM) : sbu;
#pragma unroll
  for (int m = 0; m < 4; ++m) {
#pragma unroll
    for (int q = 0; q < 4; ++q) {
      const int r = wr + m * 16 + (lane >> 4) * 4 + q;
      const int ig = mt * 128 + r;
      if (ig < rows) {
        const float wrow = wts[off + ig];
        const size_t rowbase = (size_t)(off + ig) * F_DIM + n0;
#pragma unroll
        for (int n = 0; n < 4; ++n) {
          const int c = wc + n * 16 + fr;
          const float v = acc[m][n][q] + bug[n0 + c];
          Aout[rowbase + c] = f2bf(gelu_exact(v) * wrow);
        }
      }
    }
  }
}

// ---------------- 5. grouped down-GEMM -> Y[token][slot][h] ----------------
__global__ __launch_bounds__(256) void down_gemm(const ushort_t* __restrict__ Ain,
                                                 const ushort_t* __restrict__ Wdb,
                                                 const int* __restrict__ counts,
                                                 const int* __restrict__ offs,
                                                 const int* __restrict__ rid,
                                                 float* __restrict__ Y) {
  const int g = blockIdx.y >> 4;
  const int mt = blockIdx.y & 15;
  const int rows = counts[g];
  if (mt * 128 >= rows) return;
  const int off = offs[g];
  const int n0 = blockIdx.x * 128;

  __shared__ ushort_t lA[128 * LDS_STRIDE];
  __shared__ ushort_t lB[128 * LDS_STRIDE];

  const int tid = threadIdx.x;
  const int lane = tid & 63;
  const int wid = tid >> 6;
  const int rs0 = tid >> 2;
  const int cb = (tid & 3) * 8;

  // packed A rows are contiguous; rows past `rows` stay inside the 6144-row buffer
  const ushort_t* srcA0 = Ain + (size_t)(off + mt * 128 + rs0) * F_DIM + cb;
  const ushort_t* srcA1 = srcA0 + (size_t)64 * F_DIM;
  const ushort_t* Wg = Wdb + (size_t)g * H_DIM * F_DIM;
  const ushort_t* srcB0 = Wg + (size_t)(n0 + rs0) * F_DIM + cb;
  const ushort_t* srcB1 = srcB0 + (size_t)64 * F_DIM;

  f32x4 acc[4][4];
#pragma unroll
  for (int m = 0; m < 4; ++m)
#pragma unroll
    for (int n = 0; n < 4; ++n) acc[m][n] = (f32x4){0.f, 0.f, 0.f, 0.f};

  const int wr = (wid >> 1) * 64;
  const int wc = (wid & 1) * 64;
  const int fr = lane & 15;
  const int fk = (lane >> 4) * 8;

  for (int k0 = 0; k0 < F_DIM; k0 += 32) {
    const bf16x8 va0 = *(const bf16x8*)(srcA0 + k0);
    const bf16x8 va1 = *(const bf16x8*)(srcA1 + k0);
    const bf16x8 vb0 = *(const bf16x8*)(srcB0 + k0);
    const bf16x8 vb1 = *(const bf16x8*)(srcB1 + k0);
    __syncthreads();
    *(bf16x8*)&lA[rs0 * LDS_STRIDE + cb] = va0;
    *(bf16x8*)&lA[(rs0 + 64) * LDS_STRIDE + cb] = va1;
    *(bf16x8*)&lB[rs0 * LDS_STRIDE + cb] = vb0;
    *(bf16x8*)&lB[(rs0 + 64) * LDS_STRIDE + cb] = vb1;
    __syncthreads();
    bf16x8 af[4], bfr[4];
#pragma unroll
    for (int m = 0; m < 4; ++m) af[m] = *(const bf16x8*)&lA[(wr + m * 16 + fr) * LDS_STRIDE + fk];
#pragma unroll
    for (int n = 0; n < 4; ++n) bfr[n] = *(const bf16x8*)&lB[(wc + n * 16 + fr) * LDS_STRIDE + fk];
#pragma unroll
    for (int m = 0; m < 4; ++m)
#pragma unroll
      for (int n = 0; n < 4; ++n)
        acc[m][n] = __builtin_amdgcn_mfma_f32_16x16x32_bf16(af[m], bfr[n], acc[m][n], 0, 0, 0);
  }

#pragma unroll
  for (int m = 0; m < 4; ++m) {
#pragma unroll
    for (int q = 0; q < 4; ++q) {
      const int r = wr + m * 16 + (lane >> 4) * 4 + q;
      const int ig = mt * 128 + r;
      if (ig < rows) {
        const int rv = rid[off + ig];
        const size_t yb = ((size_t)(rv >> 2) * 3 + (rv & 3)) * H_DIM + n0;
#pragma unroll
        for (int n = 0; n < 4; ++n) {
          const int c = wc + n * 16 + fr;
          Y[yb + c] = acc[m][n][q];
        }
      }
    }
  }
}

// ---------------- 6. combine: Y slots + bias terms ----------------
__global__ __launch_bounds__(256) void combine_k(const float* __restrict__ Y,
                                                 const int* __restrict__ tt_idx,
                                                 const float* __restrict__ tt_w,
                                                 const float* __restrict__ bd,
                                                 const float* __restrict__ sbd,
                                                 float* __restrict__ out) {
  const int t = blockIdx.x;
  const int h = threadIdx.x * 4;
  const int e0 = tt_idx[2 * t];
  const int e1 = tt_idx[2 * t + 1];
  const float w0 = tt_w[2 * t];
  const float w1 = tt_w[2 * t + 1];
  const float4 y0 = *(const float4*)(Y + ((size_t)t * 3 + 0) * H_DIM + h);
  const float4 y1 = *(const float4*)(Y + ((size_t)t * 3 + 1) * H_DIM + h);
  const float4 y2 = *(const float4*)(Y + ((size_t)t * 3 + 2) * H_DIM + h);
  const float4 b0 = *(const float4*)(bd + (size_t)e0 * H_DIM + h);
  const float4 b1 = *(const float4*)(bd + (size_t)e1 * H_DIM + h);
  const float4 bs = *(const float4*)(sbd + h);
  float4 o;
  o.x = y0.x + y1.x + y2.x + w0 * b0.x + w1 * b1.x + 0.1f * bs.x;
  o.y = y0.y + y1.y + y2.y + w0 * b0.y + w1 * b1.y + 0.1f * bs.y;
  o.z = y0.z + y1.z + y2.z + w0 * b0.z + w1 * b1.z + 0.1f * bs.z;
  o.w = y0.w + y1.w + y2.w + w0 * b0.w + w1 * b1.w + 0.1f * bs.w;
  *(float4*)(out + (size_t)t * H_DIM + h) = o;
}

extern "C" void kernel_launch(void* const* d_in, const int* in_sizes, int n_in,
                              void* d_out, int out_size, void* d_ws, size_t ws_size,
                              hipStream_t stream) {
  (void)in_sizes; (void)n_in; (void)out_size; (void)ws_size;
  const float* x = (const float*)d_in[0];
  const float* gate_w = (const float*)d_in[1];
  const float* gate_b = (const float*)d_in[2];
  const float* Wu = (const float*)d_in[3];
  const float* bu = (const float*)d_in[4];
  const float* Wd = (const float*)d_in[5];
  const float* bd = (const float*)d_in[6];
  const float* sWu = (const float*)d_in[7];
  const float* sbu = (const float*)d_in[8];
  const float* sWd = (const float*)d_in[9];
  const float* sbd = (const float*)d_in[10];
  float* out = (float*)d_out;

  char* ws = (char*)d_ws;
  int* tt_idx = (int*)(ws + OFF_TTI);
  float* tt_w = (float*)(ws + OFF_TTW);
  int* counts = (int*)(ws + OFF_CNT);
  int* offs = (int*)(ws + OFF_OFFS);
  int* rid = (int*)(ws + OFF_RID);
  float* wts = (float*)(ws + OFF_WTS);
  ushort_t* Xbf = (ushort_t*)(ws + OFF_XBF);
  ushort_t* Wub = (ushort_t*)(ws + OFF_WUB);
  ushort_t* Wdb = (ushort_t*)(ws + OFF_WDB);
  ushort_t* A = (ushort_t*)(ws + OFF_A);
  float* Y = (float*)(ws + OFF_Y);

  hipLaunchKernelGGL(route_k, dim3(T_TOK / 4), dim3(256), 0, stream,
                     x, gate_w, gate_b, tt_idx, tt_w);
  hipLaunchKernelGGL(build_k, dim3(1), dim3(256), 0, stream,
                     tt_idx, tt_w, counts, offs, rid, wts);
  hipLaunchKernelGGL(convert_k, dim3(4096), dim3(256), 0, stream,
                     Wu, sWu, Wd, sWd, x, Wub, Wdb, Xbf);
  hipLaunchKernelGGL(up_gemm, dim3(F_DIM / 128, NG * 16), dim3(256), 0, stream,
                     Xbf, Wub, counts, offs, rid, wts, bu, sbu, A);
  hipLaunchKernelGGL(down_gemm, dim3(H_DIM / 128, NG * 16), dim3(256), 0, stream,
                     A, Wdb, counts, offs, rid, Y);
  hipLaunchKernelGGL(combine_k, dim3(T_TOK), dim3(256), 0, stream,
                     Y, tt_idx, tt_w, bd, sbd, out);
}

// Round 3
// 633.595 us; speedup vs baseline: 1.0243x; 1.0243x over previous
//
#include <hip/hip_runtime.h>
#include <cstdint>
#include <cstddef>

// Problem constants (B=2, S=1024, H=1024, E=8, K=2, F=4096)
#define T_TOK 2048
#define H_DIM 1024
#define E_NUM 8
#define F_DIM 4096
#define NG 9          // 8 experts + 1 shared

typedef unsigned short ushort_t;
typedef __attribute__((ext_vector_type(8))) short bf16x8;
typedef __attribute__((ext_vector_type(4))) float f32x4;
typedef unsigned int u32;
typedef u32 __attribute__((address_space(3))) lds_u32;
typedef u32 __attribute__((address_space(1))) glob_u32;

// ---- workspace layout (bytes) ----
constexpr size_t OFF_TTI = 0;               // int[4096]   top-2 expert idx per token
constexpr size_t OFF_TTW = 16u << 10;       // float[4096] top-2 weights per token
constexpr size_t OFF_CNT = 32u << 10;       // int[16]     per-group row counts
constexpr size_t OFF_OFFS = (32u << 10) + 256; // int[16]  per-group packed offsets
constexpr size_t OFF_RID = 64u << 10;       // int[6144]   token<<2 | slot
constexpr size_t OFF_WTS = 96u << 10;       // float[6144] combine weight per packed row
constexpr size_t OFF_XBF = 1u << 20;        // bf16 x      [2048][1024]   (4MB)
constexpr size_t OFF_WUB = 8u << 20;        // bf16 Wu     [9][4096][1024] (72MB)
constexpr size_t OFF_WDB = 80u << 20;       // bf16 Wd     [9][1024][4096] (72MB)
constexpr size_t OFF_A   = 152u << 20;      // bf16 act    [6144][4096]   (48MB)
// total 200MB

__device__ __forceinline__ ushort_t f2bf(float f) {
  union { float f; unsigned u; } v; v.f = f;
  unsigned r = v.u + 0x7FFFu + ((v.u >> 16) & 1u);
  return (ushort_t)(r >> 16);
}

__device__ __forceinline__ float gelu_exact(float v) {
  return 0.5f * v * (1.0f + erff(v * 0.70710678118654752f));
}

// async global->LDS, 16B per lane; LDS dest must be wave-uniform base (+lane*16 HW)
__device__ __forceinline__ void gll16(const ushort_t* g, ushort_t* l) {
  __builtin_amdgcn_global_load_lds((glob_u32*)(g), (lds_u32*)(l), 16, 0, 0);
}

// ---------------- 1. routing: one wave per token ----------------
__global__ __launch_bounds__(256) void route_k(const float* __restrict__ x,
                                               const float* __restrict__ gw,
                                               const float* __restrict__ gb,
                                               int* __restrict__ tt_idx,
                                               float* __restrict__ tt_w) {
  const int lane = threadIdx.x & 63;
  const int wid = threadIdx.x >> 6;
  const int t = blockIdx.x * 4 + wid;
  if (t >= T_TOK) return;
  const float* xr = x + (size_t)t * H_DIM;
  float acc[8] = {0.f, 0.f, 0.f, 0.f, 0.f, 0.f, 0.f, 0.f};
  for (int i = 0; i < H_DIM; i += 64) {
    const int k = i + lane;
    const float xv = xr[k];
#pragma unroll
    for (int e = 0; e < 8; ++e) acc[e] = fmaf(xv, gw[e * H_DIM + k], acc[e]);
  }
#pragma unroll
  for (int e = 0; e < 8; ++e) {
    float v = acc[e];
#pragma unroll
    for (int s = 32; s; s >>= 1) v += __shfl_xor(v, s, 64);
    acc[e] = v;
  }
  if (lane == 0) {
    float sc[8];
#pragma unroll
    for (int e = 0; e < 8; ++e) sc[e] = 1.0f / (1.0f + expf(-(acc[e] + gb[e])));
    int i0 = 0;
#pragma unroll
    for (int e = 1; e < 8; ++e) if (sc[e] > sc[i0]) i0 = e;
    int i1 = (i0 == 0) ? 1 : 0;
#pragma unroll
    for (int e = 0; e < 8; ++e) if (e != i0 && sc[e] > sc[i1]) i1 = e;
    const float d = sc[i0] + sc[i1] + 1e-6f;
    tt_idx[2 * t] = i0;
    tt_idx[2 * t + 1] = i1;
    tt_w[2 * t] = sc[i0] / d;
    tt_w[2 * t + 1] = sc[i1] / d;
  }
}

// ---------------- 2. build packed per-expert lists ----------------
__global__ __launch_bounds__(256) void build_k(const int* __restrict__ tt_idx,
                                               const float* __restrict__ tt_w,
                                               int* __restrict__ counts,
                                               int* __restrict__ offs,
                                               int* __restrict__ rid,
                                               float* __restrict__ wts) {
  __shared__ int cnt[NG];
  __shared__ int cur[NG];
  const int tid = threadIdx.x;
  if (tid < NG) cnt[tid] = 0;
  __syncthreads();
  for (int p = tid; p < 2 * T_TOK; p += 256) atomicAdd(&cnt[tt_idx[p]], 1);
  __syncthreads();
  if (tid == 0) {
    int run = 0;
    for (int e = 0; e < E_NUM; ++e) {
      offs[e] = run;
      counts[e] = cnt[e];
      cur[e] = run;
      run += cnt[e];
    }
    offs[E_NUM] = 2 * T_TOK;
    counts[E_NUM] = T_TOK;
    cur[E_NUM] = 2 * T_TOK;
  }
  __syncthreads();
  for (int p = tid; p < 2 * T_TOK; p += 256) {
    const int e = tt_idx[p];
    const int pos = atomicAdd(&cur[e], 1);
    rid[pos] = ((p >> 1) << 2) | (p & 1);
    wts[pos] = tt_w[p];
  }
  for (int p = tid; p < T_TOK; p += 256) {
    rid[2 * T_TOK + p] = (p << 2) | 2;
    wts[2 * T_TOK + p] = 0.1f;
  }
}

// ---------------- 3. f32 -> bf16 conversion of weights + x ----------------
__global__ __launch_bounds__(256) void convert_k(const float* __restrict__ Wu,
                                                 const float* __restrict__ sWu,
                                                 const float* __restrict__ Wd,
                                                 const float* __restrict__ sWd,
                                                 const float* __restrict__ x,
                                                 ushort_t* __restrict__ Wub,
                                                 ushort_t* __restrict__ Wdb,
                                                 ushort_t* __restrict__ Xbf) {
  const long WE = (long)NG * F_DIM * H_DIM;   // 37748736
  const long W8 = (long)8 * F_DIM * H_DIM;    // 33554432
  const long XE = (long)T_TOK * H_DIM;        // 2097152
  const long total = (2 * WE + XE) / 8;
  for (long i = blockIdx.x * 256L + threadIdx.x; i < total; i += (long)gridDim.x * 256L) {
    const long base = i * 8;
    const float* src;
    ushort_t* dst;
    if (base < WE) {
      const long o = base;
      src = (o < W8) ? (Wu + o) : (sWu + (o - W8));
      dst = Wub + o;
    } else if (base < 2 * WE) {
      const long o = base - WE;
      src = (o < W8) ? (Wd + o) : (sWd + (o - W8));
      dst = Wdb + o;
    } else {
      const long o = base - 2 * WE;
      src = x + o;
      dst = Xbf + o;
    }
    const float4 v0 = *(const float4*)src;
    const float4 v1 = *(const float4*)(src + 4);
    bf16x8 r;
    r[0] = (short)f2bf(v0.x); r[1] = (short)f2bf(v0.y);
    r[2] = (short)f2bf(v0.z); r[3] = (short)f2bf(v0.w);
    r[4] = (short)f2bf(v1.x); r[5] = (short)f2bf(v1.y);
    r[6] = (short)f2bf(v1.z); r[7] = (short)f2bf(v1.w);
    *(bf16x8*)dst = r;
  }
}

// ---------------- 4. init out with bias terms ----------------
__global__ __launch_bounds__(256) void bias_init(const int* __restrict__ tt_idx,
                                                 const float* __restrict__ tt_w,
                                                 const float* __restrict__ bd,
                                                 const float* __restrict__ sbd,
                                                 float* __restrict__ out) {
  const int t = blockIdx.x;
  const int h = threadIdx.x * 4;
  const int e0 = tt_idx[2 * t];
  const int e1 = tt_idx[2 * t + 1];
  const float w0 = tt_w[2 * t];
  const float w1 = tt_w[2 * t + 1];
  const float4 b0 = *(const float4*)(bd + (size_t)e0 * H_DIM + h);
  const float4 b1 = *(const float4*)(bd + (size_t)e1 * H_DIM + h);
  const float4 bs = *(const float4*)(sbd + h);
  float4 o;
  o.x = w0 * b0.x + w1 * b1.x + 0.1f * bs.x;
  o.y = w0 * b0.y + w1 * b1.y + 0.1f * bs.y;
  o.z = w0 * b0.z + w1 * b1.z + 0.1f * bs.z;
  o.w = w0 * b0.w + w1 * b1.w + 0.1f * bs.w;
  *(float4*)(out + (size_t)t * H_DIM + h) = o;
}

// ---------------- 5. grouped up-GEMM + bias + GELU + weight scaling ----------------
// 128x128 tile, BK=64, global_load_lds staging with XOR-swizzled source.
// LDS chunk (row r, pos p) holds global chunk (p ^ (r&7)); reads XOR the same way.
__global__ __launch_bounds__(256) void up_gemm(const ushort_t* __restrict__ Xbf,
                                               const ushort_t* __restrict__ Wub,
                                               const int* __restrict__ counts,
                                               const int* __restrict__ offs,
                                               const int* __restrict__ rid,
                                               const float* __restrict__ wts,
                                               const float* __restrict__ bu,
                                               const float* __restrict__ sbu,
                                               ushort_t* __restrict__ Aout) {
  const int g = blockIdx.y >> 4;
  const int mt = blockIdx.y & 15;
  const int rows = counts[g];
  if (mt * 128 >= rows) return;
  const int off = offs[g];
  const int n0 = blockIdx.x * 128;

  __shared__ ushort_t lA[128 * 64];
  __shared__ ushort_t lB[128 * 64];

  const int tid = threadIdx.x;
  const int lane = tid & 63;
  const int wid = tid >> 6;
  const int sr = lane >> 3;          // sub-row within 8-row segment
  const int swz = ((lane & 7) ^ sr) << 3;  // pre-swizzled source chunk offset (elems)

  const ushort_t* Wg = Wub + (size_t)g * F_DIM * H_DIM;
  const ushort_t* pA[4];
  const ushort_t* pB[4];
#pragma unroll
  for (int i = 0; i < 4; ++i) {
    const int rA = (wid * 4 + i) * 8 + sr;   // tile row 0..127
    int ig = mt * 128 + rA;
    if (ig >= rows) ig = rows - 1;
    pA[i] = Xbf + (size_t)(rid[off + ig] >> 2) * H_DIM + swz;
    pB[i] = Wg + (size_t)(n0 + rA) * H_DIM + swz;
  }

  f32x4 acc[4][4];
#pragma unroll
  for (int m = 0; m < 4; ++m)
#pragma unroll
    for (int n = 0; n < 4; ++n) acc[m][n] = (f32x4){0.f, 0.f, 0.f, 0.f};

  const int wr = (wid >> 1) * 64;
  const int wc = (wid & 1) * 64;
  const int fr = lane & 15;
  const int hi = lane >> 4;          // 0..3

  for (int k0 = 0; k0 < H_DIM; k0 += 64) {
    __syncthreads();
#pragma unroll
    for (int i = 0; i < 4; ++i) {
      gll16(pA[i] + k0, &lA[(wid * 4 + i) * 512]);
      gll16(pB[i] + k0, &lB[(wid * 4 + i) * 512]);
    }
    __syncthreads();
#pragma unroll
    for (int ks = 0; ks < 2; ++ks) {
      const int cc = ks * 4 + hi;
      bf16x8 af[4], bv[4];
#pragma unroll
      for (int m = 0; m < 4; ++m) {
        const int r = wr + m * 16 + fr;
        af[m] = *(const bf16x8*)&lA[r * 64 + ((cc ^ (r & 7)) << 3)];
      }
#pragma unroll
      for (int n = 0; n < 4; ++n) {
        const int r = wc + n * 16 + fr;
        bv[n] = *(const bf16x8*)&lB[r * 64 + ((cc ^ (r & 7)) << 3)];
      }
#pragma unroll
      for (int m = 0; m < 4; ++m)
#pragma unroll
        for (int n = 0; n < 4; ++n)
          acc[m][n] = __builtin_amdgcn_mfma_f32_16x16x32_bf16(af[m], bv[n], acc[m][n], 0, 0, 0);
    }
  }

  const float* bug = (g < E_NUM) ? (bu + (size_t)g * F_DIM) : sbu;
#pragma unroll
  for (int m = 0; m < 4; ++m) {
#pragma unroll
    for (int q = 0; q < 4; ++q) {
      const int r = wr + m * 16 + hi * 4 + q;
      const int ig = mt * 128 + r;
      if (ig < rows) {
        const float wrow = wts[off + ig];
        const size_t rowbase = (size_t)(off + ig) * F_DIM + n0;
#pragma unroll
        for (int n = 0; n < 4; ++n) {
          const int c = wc + n * 16 + fr;
          const float v = acc[m][n][q] + bug[n0 + c];
          Aout[rowbase + c] = f2bf(gelu_exact(v) * wrow);
        }
      }
    }
  }
}

// ---------------- 6. grouped down-GEMM, split-K x4, atomic into out ----------------
__global__ __launch_bounds__(256) void down_gemm(const ushort_t* __restrict__ Ain,
                                                 const ushort_t* __restrict__ Wdb,
                                                 const int* __restrict__ counts,
                                                 const int* __restrict__ offs,
                                                 const int* __restrict__ rid,
                                                 float* __restrict__ out) {
  const int g = blockIdx.y >> 4;
  const int mt = blockIdx.y & 15;
  const int rows = counts[g];
  if (mt * 128 >= rows) return;
  const int off = offs[g];
  const int n0 = blockIdx.x * 128;
  const int kbase = blockIdx.z * 1024;   // split-K chunk

  __shared__ ushort_t lA[128 * 64];
  __shared__ ushort_t lB[128 * 64];

  const int tid = threadIdx.x;
  const int lane = tid & 63;
  const int wid = tid >> 6;
  const int sr = lane >> 3;
  const int swz = ((lane & 7) ^ sr) << 3;

  const ushort_t* Wg = Wdb + (size_t)g * H_DIM * F_DIM;
  const ushort_t* pA[4];
  const ushort_t* pB[4];
#pragma unroll
  for (int i = 0; i < 4; ++i) {
    const int rA = (wid * 4 + i) * 8 + sr;
    // packed A rows contiguous; overreads past `rows` stay inside the 6144-row buffer
    pA[i] = Ain + (size_t)(off + mt * 128 + rA) * F_DIM + kbase + swz;
    pB[i] = Wg + (size_t)(n0 + rA) * F_DIM + kbase + swz;
  }

  f32x4 acc[4][4];
#pragma unroll
  for (int m = 0; m < 4; ++m)
#pragma unroll
    for (int n = 0; n < 4; ++n) acc[m][n] = (f32x4){0.f, 0.f, 0.f, 0.f};

  const int wr = (wid >> 1) * 64;
  const int wc = (wid & 1) * 64;
  const int fr = lane & 15;
  const int hi = lane >> 4;

  for (int k0 = 0; k0 < 1024; k0 += 64) {
    __syncthreads();
#pragma unroll
    for (int i = 0; i < 4; ++i) {
      gll16(pA[i] + k0, &lA[(wid * 4 + i) * 512]);
      gll16(pB[i] + k0, &lB[(wid * 4 + i) * 512]);
    }
    __syncthreads();
#pragma unroll
    for (int ks = 0; ks < 2; ++ks) {
      const int cc = ks * 4 + hi;
      bf16x8 af[4], bv[4];
#pragma unroll
      for (int m = 0; m < 4; ++m) {
        const int r = wr + m * 16 + fr;
        af[m] = *(const bf16x8*)&lA[r * 64 + ((cc ^ (r & 7)) << 3)];
      }
#pragma unroll
      for (int n = 0; n < 4; ++n) {
        const int r = wc + n * 16 + fr;
        bv[n] = *(const bf16x8*)&lB[r * 64 + ((cc ^ (r & 7)) << 3)];
      }
#pragma unroll
      for (int m = 0; m < 4; ++m)
#pragma unroll
        for (int n = 0; n < 4; ++n)
          acc[m][n] = __builtin_amdgcn_mfma_f32_16x16x32_bf16(af[m], bv[n], acc[m][n], 0, 0, 0);
    }
  }

#pragma unroll
  for (int m = 0; m < 4; ++m) {
#pragma unroll
    for (int q = 0; q < 4; ++q) {
      const int r = wr + m * 16 + hi * 4 + q;
      const int ig = mt * 128 + r;
      if (ig < rows) {
        const int rv = rid[off + ig];
        float* orow = out + (size_t)(rv >> 2) * H_DIM + n0;
#pragma unroll
        for (int n = 0; n < 4; ++n) {
          const int c = wc + n * 16 + fr;
          unsafeAtomicAdd(&orow[c], acc[m][n][q]);
        }
      }
    }
  }
}

extern "C" void kernel_launch(void* const* d_in, const int* in_sizes, int n_in,
                              void* d_out, int out_size, void* d_ws, size_t ws_size,
                              hipStream_t stream) {
  (void)in_sizes; (void)n_in; (void)out_size; (void)ws_size;
  const float* x = (const float*)d_in[0];
  const float* gate_w = (const float*)d_in[1];
  const float* gate_b = (const float*)d_in[2];
  const float* Wu = (const float*)d_in[3];
  const float* bu = (const float*)d_in[4];
  const float* Wd = (const float*)d_in[5];
  const float* bd = (const float*)d_in[6];
  const float* sWu = (const float*)d_in[7];
  const float* sbu = (const float*)d_in[8];
  const float* sWd = (const float*)d_in[9];
  const float* sbd = (const float*)d_in[10];
  float* out = (float*)d_out;

  char* ws = (char*)d_ws;
  int* tt_idx = (int*)(ws + OFF_TTI);
  float* tt_w = (float*)(ws + OFF_TTW);
  int* counts = (int*)(ws + OFF_CNT);
  int* offs = (int*)(ws + OFF_OFFS);
  int* rid = (int*)(ws + OFF_RID);
  float* wts = (float*)(ws + OFF_WTS);
  ushort_t* Xbf = (ushort_t*)(ws + OFF_XBF);
  ushort_t* Wub = (ushort_t*)(ws + OFF_WUB);
  ushort_t* Wdb = (ushort_t*)(ws + OFF_WDB);
  ushort_t* A = (ushort_t*)(ws + OFF_A);

  hipLaunchKernelGGL(route_k, dim3(T_TOK / 4), dim3(256), 0, stream,
                     x, gate_w, gate_b, tt_idx, tt_w);
  hipLaunchKernelGGL(build_k, dim3(1), dim3(256), 0, stream,
                     tt_idx, tt_w, counts, offs, rid, wts);
  hipLaunchKernelGGL(bias_init, dim3(T_TOK), dim3(256), 0, stream,
                     tt_idx, tt_w, bd, sbd, out);
  hipLaunchKernelGGL(convert_k, dim3(4096), dim3(256), 0, stream,
                     Wu, sWu, Wd, sWd, x, Wub, Wdb, Xbf);
  hipLaunchKernelGGL(up_gemm, dim3(F_DIM / 128, NG * 16), dim3(256), 0, stream,
                     Xbf, Wub, counts, offs, rid, wts, bu, sbu, A);
  hipLaunchKernelGGL(down_gemm, dim3(H_DIM / 128, NG * 16, 4), dim3(256), 0, stream,
                     A, Wdb, counts, offs, rid, out);
}

// Round 4
// 593.558 us; speedup vs baseline: 1.0934x; 1.0675x over previous
//
#include <hip/hip_runtime.h>
#include <cstdint>
#include <cstddef>

// Problem constants (B=2, S=1024, H=1024, E=8, K=2, F=4096)
#define T_TOK 2048
#define H_DIM 1024
#define E_NUM 8
#define F_DIM 4096
#define NG 9          // 8 experts + 1 shared

typedef unsigned short ushort_t;
typedef __attribute__((ext_vector_type(8))) short bf16x8;
typedef __attribute__((ext_vector_type(4))) float f32x4;
typedef unsigned int u32;
typedef u32 __attribute__((address_space(3))) lds_u32;
typedef u32 __attribute__((address_space(1))) glob_u32;

// ---- workspace layout (bytes) ----
constexpr size_t OFF_TTI = 0;               // int[4096]   top-2 expert idx per token
constexpr size_t OFF_TTW = 16u << 10;       // float[4096] top-2 weights per token
constexpr size_t OFF_CNT = 32u << 10;       // int[16]     per-group row counts
constexpr size_t OFF_OFFS = (32u << 10) + 256; // int[16]  per-group packed offsets
constexpr size_t OFF_RID = 64u << 10;       // int[6144]   token<<2 | slot
constexpr size_t OFF_WTS = 96u << 10;       // float[6144] combine weight per packed row
constexpr size_t OFF_XBF = 1u << 20;        // bf16 x      [2048][1024]   (4MB)
constexpr size_t OFF_WUB = 8u << 20;        // bf16 Wu     [9][4096][1024] (72MB)
constexpr size_t OFF_WDB = 80u << 20;       // bf16 Wd     [9][1024][4096] (72MB)
constexpr size_t OFF_A   = 152u << 20;      // bf16 act    [6144][4096]   (48MB)
constexpr size_t OFF_Y   = 200u << 20;      // bf16 Y      [2][2048][3][1024] (24MB)
// total 224MB (proven bound from R1)
constexpr size_t Y_SPLIT_STRIDE = (size_t)T_TOK * 3 * H_DIM;  // elems per split copy

__device__ __forceinline__ ushort_t f2bf(float f) {
  union { float f; unsigned u; } v; v.f = f;
  unsigned r = v.u + 0x7FFFu + ((v.u >> 16) & 1u);
  return (ushort_t)(r >> 16);
}

__device__ __forceinline__ float bf2f(ushort_t b) {
  union { unsigned u; float f; } v; v.u = ((unsigned)b) << 16;
  return v.f;
}

__device__ __forceinline__ float gelu_exact(float v) {
  return 0.5f * v * (1.0f + erff(v * 0.70710678118654752f));
}

// async global->LDS, 16B per lane; LDS dest must be wave-uniform base (+lane*16 HW)
__device__ __forceinline__ void gll16(const ushort_t* g, ushort_t* l) {
  __builtin_amdgcn_global_load_lds((glob_u32*)(g), (lds_u32*)(l), 16, 0, 0);
}

// ---------------- 1. routing: one wave per token ----------------
__global__ __launch_bounds__(256) void route_k(const float* __restrict__ x,
                                               const float* __restrict__ gw,
                                               const float* __restrict__ gb,
                                               int* __restrict__ tt_idx,
                                               float* __restrict__ tt_w) {
  const int lane = threadIdx.x & 63;
  const int wid = threadIdx.x >> 6;
  const int t = blockIdx.x * 4 + wid;
  if (t >= T_TOK) return;
  const float* xr = x + (size_t)t * H_DIM;
  float acc[8] = {0.f, 0.f, 0.f, 0.f, 0.f, 0.f, 0.f, 0.f};
  for (int i = 0; i < H_DIM; i += 64) {
    const int k = i + lane;
    const float xv = xr[k];
#pragma unroll
    for (int e = 0; e < 8; ++e) acc[e] = fmaf(xv, gw[e * H_DIM + k], acc[e]);
  }
#pragma unroll
  for (int e = 0; e < 8; ++e) {
    float v = acc[e];
#pragma unroll
    for (int s = 32; s; s >>= 1) v += __shfl_xor(v, s, 64);
    acc[e] = v;
  }
  if (lane == 0) {
    float sc[8];
#pragma unroll
    for (int e = 0; e < 8; ++e) sc[e] = 1.0f / (1.0f + expf(-(acc[e] + gb[e])));
    int i0 = 0;
#pragma unroll
    for (int e = 1; e < 8; ++e) if (sc[e] > sc[i0]) i0 = e;
    int i1 = (i0 == 0) ? 1 : 0;
#pragma unroll
    for (int e = 0; e < 8; ++e) if (e != i0 && sc[e] > sc[i1]) i1 = e;
    const float d = sc[i0] + sc[i1] + 1e-6f;
    tt_idx[2 * t] = i0;
    tt_idx[2 * t + 1] = i1;
    tt_w[2 * t] = sc[i0] / d;
    tt_w[2 * t + 1] = sc[i1] / d;
  }
}

// ---------------- 2. build packed per-expert lists ----------------
__global__ __launch_bounds__(256) void build_k(const int* __restrict__ tt_idx,
                                               const float* __restrict__ tt_w,
                                               int* __restrict__ counts,
                                               int* __restrict__ offs,
                                               int* __restrict__ rid,
                                               float* __restrict__ wts) {
  __shared__ int cnt[NG];
  __shared__ int cur[NG];
  const int tid = threadIdx.x;
  if (tid < NG) cnt[tid] = 0;
  __syncthreads();
  for (int p = tid; p < 2 * T_TOK; p += 256) atomicAdd(&cnt[tt_idx[p]], 1);
  __syncthreads();
  if (tid == 0) {
    int run = 0;
    for (int e = 0; e < E_NUM; ++e) {
      offs[e] = run;
      counts[e] = cnt[e];
      cur[e] = run;
      run += cnt[e];
    }
    offs[E_NUM] = 2 * T_TOK;
    counts[E_NUM] = T_TOK;
    cur[E_NUM] = 2 * T_TOK;
  }
  __syncthreads();
  for (int p = tid; p < 2 * T_TOK; p += 256) {
    const int e = tt_idx[p];
    const int pos = atomicAdd(&cur[e], 1);
    rid[pos] = ((p >> 1) << 2) | (p & 1);
    wts[pos] = tt_w[p];
  }
  for (int p = tid; p < T_TOK; p += 256) {
    rid[2 * T_TOK + p] = (p << 2) | 2;
    wts[2 * T_TOK + p] = 0.1f;
  }
}

// ---------------- 3. f32 -> bf16 conversion of weights + x ----------------
__global__ __launch_bounds__(256) void convert_k(const float* __restrict__ Wu,
                                                 const float* __restrict__ sWu,
                                                 const float* __restrict__ Wd,
                                                 const float* __restrict__ sWd,
                                                 const float* __restrict__ x,
                                                 ushort_t* __restrict__ Wub,
                                                 ushort_t* __restrict__ Wdb,
                                                 ushort_t* __restrict__ Xbf) {
  const long WE = (long)NG * F_DIM * H_DIM;   // 37748736
  const long W8 = (long)8 * F_DIM * H_DIM;    // 33554432
  const long XE = (long)T_TOK * H_DIM;        // 2097152
  const long total = (2 * WE + XE) / 8;
  for (long i = blockIdx.x * 256L + threadIdx.x; i < total; i += (long)gridDim.x * 256L) {
    const long base = i * 8;
    const float* src;
    ushort_t* dst;
    if (base < WE) {
      const long o = base;
      src = (o < W8) ? (Wu + o) : (sWu + (o - W8));
      dst = Wub + o;
    } else if (base < 2 * WE) {
      const long o = base - WE;
      src = (o < W8) ? (Wd + o) : (sWd + (o - W8));
      dst = Wdb + o;
    } else {
      const long o = base - 2 * WE;
      src = x + o;
      dst = Xbf + o;
    }
    const float4 v0 = *(const float4*)src;
    const float4 v1 = *(const float4*)(src + 4);
    bf16x8 r;
    r[0] = (short)f2bf(v0.x); r[1] = (short)f2bf(v0.y);
    r[2] = (short)f2bf(v0.z); r[3] = (short)f2bf(v0.w);
    r[4] = (short)f2bf(v1.x); r[5] = (short)f2bf(v1.y);
    r[6] = (short)f2bf(v1.z); r[7] = (short)f2bf(v1.w);
    *(bf16x8*)dst = r;
  }
}

// ---------------- 4. grouped up-GEMM + bias + GELU + weight scaling ----------------
// 128x128 tile, BK=64, global_load_lds staging with XOR-swizzled source.
// LDS chunk (row r, pos p) holds global chunk (p ^ (r&7)); reads XOR the same way.
__global__ __launch_bounds__(256) void up_gemm(const ushort_t* __restrict__ Xbf,
                                               const ushort_t* __restrict__ Wub,
                                               const int* __restrict__ counts,
                                               const int* __restrict__ offs,
                                               const int* __restrict__ rid,
                                               const float* __restrict__ wts,
                                               const float* __restrict__ bu,
                                               const float* __restrict__ sbu,
                                               ushort_t* __restrict__ Aout) {
  const int g = blockIdx.y >> 4;
  const int mt = blockIdx.y & 15;
  const int rows = counts[g];
  if (mt * 128 >= rows) return;
  const int off = offs[g];
  const int n0 = blockIdx.x * 128;

  __shared__ ushort_t lA[128 * 64];
  __shared__ ushort_t lB[128 * 64];

  const int tid = threadIdx.x;
  const int lane = tid & 63;
  const int wid = tid >> 6;
  const int sr = lane >> 3;          // sub-row within 8-row segment
  const int swz = ((lane & 7) ^ sr) << 3;  // pre-swizzled source chunk offset (elems)

  const ushort_t* Wg = Wub + (size_t)g * F_DIM * H_DIM;
  const ushort_t* pA[4];
  const ushort_t* pB[4];
#pragma unroll
  for (int i = 0; i < 4; ++i) {
    const int rA = (wid * 4 + i) * 8 + sr;   // tile row 0..127
    int ig = mt * 128 + rA;
    if (ig >= rows) ig = rows - 1;
    pA[i] = Xbf + (size_t)(rid[off + ig] >> 2) * H_DIM + swz;
    pB[i] = Wg + (size_t)(n0 + rA) * H_DIM + swz;
  }

  f32x4 acc[4][4];
#pragma unroll
  for (int m = 0; m < 4; ++m)
#pragma unroll
    for (int n = 0; n < 4; ++n) acc[m][n] = (f32x4){0.f, 0.f, 0.f, 0.f};

  const int wr = (wid >> 1) * 64;
  const int wc = (wid & 1) * 64;
  const int fr = lane & 15;
  const int hi = lane >> 4;          // 0..3

  for (int k0 = 0; k0 < H_DIM; k0 += 64) {
    __syncthreads();
#pragma unroll
    for (int i = 0; i < 4; ++i) {
      gll16(pA[i] + k0, &lA[(wid * 4 + i) * 512]);
      gll16(pB[i] + k0, &lB[(wid * 4 + i) * 512]);
    }
    __syncthreads();
#pragma unroll
    for (int ks = 0; ks < 2; ++ks) {
      const int cc = ks * 4 + hi;
      bf16x8 af[4], bv[4];
#pragma unroll
      for (int m = 0; m < 4; ++m) {
        const int r = wr + m * 16 + fr;
        af[m] = *(const bf16x8*)&lA[r * 64 + ((cc ^ (r & 7)) << 3)];
      }
#pragma unroll
      for (int n = 0; n < 4; ++n) {
        const int r = wc + n * 16 + fr;
        bv[n] = *(const bf16x8*)&lB[r * 64 + ((cc ^ (r & 7)) << 3)];
      }
#pragma unroll
      for (int m = 0; m < 4; ++m)
#pragma unroll
        for (int n = 0; n < 4; ++n)
          acc[m][n] = __builtin_amdgcn_mfma_f32_16x16x32_bf16(af[m], bv[n], acc[m][n], 0, 0, 0);
    }
  }

  const float* bug = (g < E_NUM) ? (bu + (size_t)g * F_DIM) : sbu;
#pragma unroll
  for (int m = 0; m < 4; ++m) {
#pragma unroll
    for (int q = 0; q < 4; ++q) {
      const int r = wr + m * 16 + hi * 4 + q;
      const int ig = mt * 128 + r;
      if (ig < rows) {
        const float wrow = wts[off + ig];
        const size_t rowbase = (size_t)(off + ig) * F_DIM + n0;
#pragma unroll
        for (int n = 0; n < 4; ++n) {
          const int c = wc + n * 16 + fr;
          const float v = acc[m][n][q] + bug[n0 + c];
          Aout[rowbase + c] = f2bf(gelu_exact(v) * wrow);
        }
      }
    }
  }
}

// ---------------- 5. grouped down-GEMM, split-K x2, deterministic bf16 Y scatter ----------------
__global__ __launch_bounds__(256) void down_gemm(const ushort_t* __restrict__ Ain,
                                                 const ushort_t* __restrict__ Wdb,
                                                 const int* __restrict__ counts,
                                                 const int* __restrict__ offs,
                                                 const int* __restrict__ rid,
                                                 ushort_t* __restrict__ Ybf) {
  const int g = blockIdx.y >> 4;
  const int mt = blockIdx.y & 15;
  const int rows = counts[g];
  if (mt * 128 >= rows) return;
  const int off = offs[g];
  const int n0 = blockIdx.x * 128;
  const int kbase = blockIdx.z * 2048;   // split-K chunk (2 splits)
  ushort_t* Ys = Ybf + (size_t)blockIdx.z * Y_SPLIT_STRIDE;

  __shared__ ushort_t lA[128 * 64];
  __shared__ ushort_t lB[128 * 64];

  const int tid = threadIdx.x;
  const int lane = tid & 63;
  const int wid = tid >> 6;
  const int sr = lane >> 3;
  const int swz = ((lane & 7) ^ sr) << 3;

  const ushort_t* Wg = Wdb + (size_t)g * H_DIM * F_DIM;
  const ushort_t* pA[4];
  const ushort_t* pB[4];
#pragma unroll
  for (int i = 0; i < 4; ++i) {
    const int rA = (wid * 4 + i) * 8 + sr;
    // packed A rows contiguous; overreads past `rows` stay inside the 6144-row buffer
    pA[i] = Ain + (size_t)(off + mt * 128 + rA) * F_DIM + kbase + swz;
    pB[i] = Wg + (size_t)(n0 + rA) * F_DIM + kbase + swz;
  }

  f32x4 acc[4][4];
#pragma unroll
  for (int m = 0; m < 4; ++m)
#pragma unroll
    for (int n = 0; n < 4; ++n) acc[m][n] = (f32x4){0.f, 0.f, 0.f, 0.f};

  const int wr = (wid >> 1) * 64;
  const int wc = (wid & 1) * 64;
  const int fr = lane & 15;
  const int hi = lane >> 4;

  for (int k0 = 0; k0 < 2048; k0 += 64) {
    __syncthreads();
#pragma unroll
    for (int i = 0; i < 4; ++i) {
      gll16(pA[i] + k0, &lA[(wid * 4 + i) * 512]);
      gll16(pB[i] + k0, &lB[(wid * 4 + i) * 512]);
    }
    __syncthreads();
#pragma unroll
    for (int ks = 0; ks < 2; ++ks) {
      const int cc = ks * 4 + hi;
      bf16x8 af[4], bv[4];
#pragma unroll
      for (int m = 0; m < 4; ++m) {
        const int r = wr + m * 16 + fr;
        af[m] = *(const bf16x8*)&lA[r * 64 + ((cc ^ (r & 7)) << 3)];
      }
#pragma unroll
      for (int n = 0; n < 4; ++n) {
        const int r = wc + n * 16 + fr;
        bv[n] = *(const bf16x8*)&lB[r * 64 + ((cc ^ (r & 7)) << 3)];
      }
#pragma unroll
      for (int m = 0; m < 4; ++m)
#pragma unroll
        for (int n = 0; n < 4; ++n)
          acc[m][n] = __builtin_amdgcn_mfma_f32_16x16x32_bf16(af[m], bv[n], acc[m][n], 0, 0, 0);
    }
  }

#pragma unroll
  for (int m = 0; m < 4; ++m) {
#pragma unroll
    for (int q = 0; q < 4; ++q) {
      const int r = wr + m * 16 + hi * 4 + q;
      const int ig = mt * 128 + r;
      if (ig < rows) {
        const int rv = rid[off + ig];
        ushort_t* yrow = Ys + ((size_t)(rv >> 2) * 3 + (rv & 3)) * H_DIM + n0;
#pragma unroll
        for (int n = 0; n < 4; ++n) {
          const int c = wc + n * 16 + fr;
          yrow[c] = f2bf(acc[m][n][q]);
        }
      }
    }
  }
}

// ---------------- 6. combine: 2 splits x 3 slots + bias terms ----------------
__global__ __launch_bounds__(256) void combine_k(const ushort_t* __restrict__ Ybf,
                                                 const int* __restrict__ tt_idx,
                                                 const float* __restrict__ tt_w,
                                                 const float* __restrict__ bd,
                                                 const float* __restrict__ sbd,
                                                 float* __restrict__ out) {
  const int t = blockIdx.x;
  const int h = threadIdx.x * 4;
  const int e0 = tt_idx[2 * t];
  const int e1 = tt_idx[2 * t + 1];
  const float w0 = tt_w[2 * t];
  const float w1 = tt_w[2 * t + 1];
  float s[4] = {0.f, 0.f, 0.f, 0.f};
#pragma unroll
  for (int sp = 0; sp < 2; ++sp) {
#pragma unroll
    for (int sl = 0; sl < 3; ++sl) {
      const ushort_t* yp = Ybf + sp * Y_SPLIT_STRIDE + ((size_t)t * 3 + sl) * H_DIM + h;
      const ushort4 v = *(const ushort4*)yp;
      s[0] += bf2f(v.x); s[1] += bf2f(v.y); s[2] += bf2f(v.z); s[3] += bf2f(v.w);
    }
  }
  const float4 b0 = *(const float4*)(bd + (size_t)e0 * H_DIM + h);
  const float4 b1 = *(const float4*)(bd + (size_t)e1 * H_DIM + h);
  const float4 bs = *(const float4*)(sbd + h);
  float4 o;
  o.x = s[0] + w0 * b0.x + w1 * b1.x + 0.1f * bs.x;
  o.y = s[1] + w0 * b0.y + w1 * b1.y + 0.1f * bs.y;
  o.z = s[2] + w0 * b0.z + w1 * b1.z + 0.1f * bs.z;
  o.w = s[3] + w0 * b0.w + w1 * b1.w + 0.1f * bs.w;
  *(float4*)(out + (size_t)t * H_DIM + h) = o;
}

extern "C" void kernel_launch(void* const* d_in, const int* in_sizes, int n_in,
                              void* d_out, int out_size, void* d_ws, size_t ws_size,
                              hipStream_t stream) {
  (void)in_sizes; (void)n_in; (void)out_size; (void)ws_size;
  const float* x = (const float*)d_in[0];
  const float* gate_w = (const float*)d_in[1];
  const float* gate_b = (const float*)d_in[2];
  const float* Wu = (const float*)d_in[3];
  const float* bu = (const float*)d_in[4];
  const float* Wd = (const float*)d_in[5];
  const float* bd = (const float*)d_in[6];
  const float* sWu = (const float*)d_in[7];
  const float* sbu = (const float*)d_in[8];
  const float* sWd = (const float*)d_in[9];
  const float* sbd = (const float*)d_in[10];
  float* out = (float*)d_out;

  char* ws = (char*)d_ws;
  int* tt_idx = (int*)(ws + OFF_TTI);
  float* tt_w = (float*)(ws + OFF_TTW);
  int* counts = (int*)(ws + OFF_CNT);
  int* offs = (int*)(ws + OFF_OFFS);
  int* rid = (int*)(ws + OFF_RID);
  float* wts = (float*)(ws + OFF_WTS);
  ushort_t* Xbf = (ushort_t*)(ws + OFF_XBF);
  ushort_t* Wub = (ushort_t*)(ws + OFF_WUB);
  ushort_t* Wdb = (ushort_t*)(ws + OFF_WDB);
  ushort_t* A = (ushort_t*)(ws + OFF_A);
  ushort_t* Y = (ushort_t*)(ws + OFF_Y);

  hipLaunchKernelGGL(route_k, dim3(T_TOK / 4), dim3(256), 0, stream,
                     x, gate_w, gate_b, tt_idx, tt_w);
  hipLaunchKernelGGL(build_k, dim3(1), dim3(256), 0, stream,
                     tt_idx, tt_w, counts, offs, rid, wts);
  hipLaunchKernelGGL(convert_k, dim3(4096), dim3(256), 0, stream,
                     Wu, sWu, Wd, sWd, x, Wub, Wdb, Xbf);
  hipLaunchKernelGGL(up_gemm, dim3(F_DIM / 128, NG * 16), dim3(256), 0, stream,
                     Xbf, Wub, counts, offs, rid, wts, bu, sbu, A);
  hipLaunchKernelGGL(down_gemm, dim3(H_DIM / 128, NG * 16, 2), dim3(256), 0, stream,
                     A, Wdb, counts, offs, rid, Y);
  hipLaunchKernelGGL(combine_k, dim3(T_TOK), dim3(256), 0, stream,
                     Y, tt_idx, tt_w, bd, sbd, out);
}

// Round 7
// 548.140 us; speedup vs baseline: 1.1840x; 1.0829x over previous
//
#include <hip/hip_runtime.h>
#include <cstdint>
#include <cstddef>

// Problem constants (B=2, S=1024, H=1024, E=8, K=2, F=4096)
#define T_TOK 2048
#define H_DIM 1024
#define E_NUM 8
#define F_DIM 4096
#define NG 9          // 8 experts + 1 shared

typedef unsigned short ushort_t;
typedef __attribute__((ext_vector_type(8))) short bf16x8;
typedef __attribute__((ext_vector_type(4))) float f32x4;
typedef unsigned int u32;
typedef u32 __attribute__((address_space(3))) lds_u32;
typedef u32 __attribute__((address_space(1))) glob_u32;

// ---- workspace layout (bytes) ----
constexpr size_t OFF_TTI = 0;               // int[4096]   top-2 expert idx per token
constexpr size_t OFF_TTW = 16u << 10;       // float[4096] top-2 weights per token
constexpr size_t OFF_CNT = 32u << 10;       // int[16]     per-group row counts
constexpr size_t OFF_OFFS = (32u << 10) + 256; // int[16]  per-group packed offsets
constexpr size_t OFF_RID = 64u << 10;       // int[6144]   token<<2 | slot
constexpr size_t OFF_WTS = 96u << 10;       // float[6144] combine weight per packed row
constexpr size_t OFF_XBF = 1u << 20;        // bf16 x      [2048][1024]   (4MB)
constexpr size_t OFF_WUB = 8u << 20;        // bf16 Wu     [9][4096][1024] (72MB)
constexpr size_t OFF_WDB = 80u << 20;       // bf16 Wd     [9][1024][4096] (72MB)
constexpr size_t OFF_A   = 152u << 20;      // bf16 act    [6144][4096]   (48MB)
constexpr size_t OFF_Y   = 200u << 20;      // bf16 Y      [2][2048][3][1024] (24MB)
// total 224MB
constexpr size_t Y_SPLIT_STRIDE = (size_t)T_TOK * 3 * H_DIM;  // elems per split copy

__device__ __forceinline__ ushort_t f2bf(float f) {
  union { float f; unsigned u; } v; v.f = f;
  unsigned r = v.u + 0x7FFFu + ((v.u >> 16) & 1u);
  return (ushort_t)(r >> 16);
}

__device__ __forceinline__ float bf2f(ushort_t b) {
  union { unsigned u; float f; } v; v.u = ((unsigned)b) << 16;
  return v.f;
}

// exact-GELU via Abramowitz-Stegun 7.1.26 erf (|err| <= 1.5e-7), ~14 VALU ops
// vs libm erff's much longer sequence. gelu(v) = 0.5 v (1 + erf(v/sqrt2)).
__device__ __forceinline__ float gelu_fast(float v) {
  const float x = v * 0.70710678118654752f;
  const float xa = fabsf(x);
  const float t = __builtin_amdgcn_rcpf(fmaf(0.3275911f, xa, 1.0f));
  float p = fmaf(1.061405429f, t, -1.453152027f);
  p = fmaf(p, t, 1.421413741f);
  p = fmaf(p, t, -0.284496736f);
  p = fmaf(p, t, 0.254829592f);
  p = p * t;
  const float e = __expf(-xa * xa);
  float erfa = fmaf(-p, e, 1.0f);          // erf(|x|)
  erfa = copysignf(erfa, x);
  return 0.5f * v * (1.0f + erfa);
}

// async global->LDS, 16B per lane; LDS dest must be wave-uniform base (+lane*16 HW)
__device__ __forceinline__ void gll16(const ushort_t* g, ushort_t* l) {
  __builtin_amdgcn_global_load_lds((glob_u32*)(g), (lds_u32*)(l), 16, 0, 0);
}

// vmcnt(0) drain + raw barrier; asm memory clobber is the compiler fence
#define VMCNT0_BARRIER do { \
  asm volatile("s_waitcnt vmcnt(0)" ::: "memory"); \
  __builtin_amdgcn_s_barrier(); \
} while (0)

// ---------------- 1. routing: one wave per token ----------------
__global__ __launch_bounds__(256) void route_k(const float* __restrict__ x,
                                               const float* __restrict__ gw,
                                               const float* __restrict__ gb,
                                               int* __restrict__ tt_idx,
                                               float* __restrict__ tt_w) {
  const int lane = threadIdx.x & 63;
  const int wid = threadIdx.x >> 6;
  const int t = blockIdx.x * 4 + wid;
  if (t >= T_TOK) return;
  const float* xr = x + (size_t)t * H_DIM;
  float acc[8] = {0.f, 0.f, 0.f, 0.f, 0.f, 0.f, 0.f, 0.f};
  for (int i = 0; i < H_DIM; i += 64) {
    const int k = i + lane;
    const float xv = xr[k];
#pragma unroll
    for (int e = 0; e < 8; ++e) acc[e] = fmaf(xv, gw[e * H_DIM + k], acc[e]);
  }
#pragma unroll
  for (int e = 0; e < 8; ++e) {
    float v = acc[e];
#pragma unroll
    for (int s = 32; s; s >>= 1) v += __shfl_xor(v, s, 64);
    acc[e] = v;
  }
  if (lane == 0) {
    float sc[8];
#pragma unroll
    for (int e = 0; e < 8; ++e) sc[e] = 1.0f / (1.0f + expf(-(acc[e] + gb[e])));
    int i0 = 0;
#pragma unroll
    for (int e = 1; e < 8; ++e) if (sc[e] > sc[i0]) i0 = e;
    int i1 = (i0 == 0) ? 1 : 0;
#pragma unroll
    for (int e = 0; e < 8; ++e) if (e != i0 && sc[e] > sc[i1]) i1 = e;
    const float d = sc[i0] + sc[i1] + 1e-6f;
    tt_idx[2 * t] = i0;
    tt_idx[2 * t + 1] = i1;
    tt_w[2 * t] = sc[i0] / d;
    tt_w[2 * t + 1] = sc[i1] / d;
  }
}

// ---------------- 2. build packed per-expert lists ----------------
__global__ __launch_bounds__(256) void build_k(const int* __restrict__ tt_idx,
                                               const float* __restrict__ tt_w,
                                               int* __restrict__ counts,
                                               int* __restrict__ offs,
                                               int* __restrict__ rid,
                                               float* __restrict__ wts) {
  __shared__ int cnt[NG];
  __shared__ int cur[NG];
  const int tid = threadIdx.x;
  if (tid < NG) cnt[tid] = 0;
  __syncthreads();
  for (int p = tid; p < 2 * T_TOK; p += 256) atomicAdd(&cnt[tt_idx[p]], 1);
  __syncthreads();
  if (tid == 0) {
    int run = 0;
    for (int e = 0; e < E_NUM; ++e) {
      offs[e] = run;
      counts[e] = cnt[e];
      cur[e] = run;
      run += cnt[e];
    }
    offs[E_NUM] = 2 * T_TOK;
    counts[E_NUM] = T_TOK;
    cur[E_NUM] = 2 * T_TOK;
  }
  __syncthreads();
  for (int p = tid; p < 2 * T_TOK; p += 256) {
    const int e = tt_idx[p];
    const int pos = atomicAdd(&cur[e], 1);
    rid[pos] = ((p >> 1) << 2) | (p & 1);
    wts[pos] = tt_w[p];
  }
  for (int p = tid; p < T_TOK; p += 256) {
    rid[2 * T_TOK + p] = (p << 2) | 2;
    wts[2 * T_TOK + p] = 0.1f;
  }
}

// ---------------- 3. f32 -> bf16 conversion of weights + x ----------------
__global__ __launch_bounds__(256) void convert_k(const float* __restrict__ Wu,
                                                 const float* __restrict__ sWu,
                                                 const float* __restrict__ Wd,
                                                 const float* __restrict__ sWd,
                                                 const float* __restrict__ x,
                                                 ushort_t* __restrict__ Wub,
                                                 ushort_t* __restrict__ Wdb,
                                                 ushort_t* __restrict__ Xbf) {
  const long WE = (long)NG * F_DIM * H_DIM;   // 37748736
  const long W8 = (long)8 * F_DIM * H_DIM;    // 33554432
  const long XE = (long)T_TOK * H_DIM;        // 2097152
  const long total = (2 * WE + XE) / 8;
  for (long i = blockIdx.x * 256L + threadIdx.x; i < total; i += (long)gridDim.x * 256L) {
    const long base = i * 8;
    const float* src;
    ushort_t* dst;
    if (base < WE) {
      const long o = base;
      src = (o < W8) ? (Wu + o) : (sWu + (o - W8));
      dst = Wub + o;
    } else if (base < 2 * WE) {
      const long o = base - WE;
      src = (o < W8) ? (Wd + o) : (sWd + (o - W8));
      dst = Wdb + o;
    } else {
      const long o = base - 2 * WE;
      src = x + o;
      dst = Xbf + o;
    }
    const float4 v0 = *(const float4*)src;
    const float4 v1 = *(const float4*)(src + 4);
    bf16x8 r;
    r[0] = (short)f2bf(v0.x); r[1] = (short)f2bf(v0.y);
    r[2] = (short)f2bf(v0.z); r[3] = (short)f2bf(v0.w);
    r[4] = (short)f2bf(v1.x); r[5] = (short)f2bf(v1.y);
    r[6] = (short)f2bf(v1.z); r[7] = (short)f2bf(v1.w);
    *(bf16x8*)dst = r;
  }
}

// ---- shared GEMM tile macros (128x128, BK=64, 2-phase prefetch) ----
// STAGE: issue 8 global_load_lds (A rows + B rows) for K-offset k0_ into bufs
#define STAGE_T(A_, B_, k0_) do { \
  _Pragma("unroll") \
  for (int i_ = 0; i_ < 4; ++i_) { \
    gll16(pA[i_] + (k0_), &(A_)[(wid * 4 + i_) * 512]); \
    gll16(pB[i_] + (k0_), &(B_)[(wid * 4 + i_) * 512]); \
  } \
} while (0)

// COMPUTE: 2 x 16 MFMA on one staged buffer pair (swizzled reads)
#define COMPUTE_T(A_, B_) do { \
  _Pragma("unroll") \
  for (int ks_ = 0; ks_ < 2; ++ks_) { \
    const int cc_ = ks_ * 4 + hi; \
    bf16x8 af_[4], bv_[4]; \
    _Pragma("unroll") \
    for (int m_ = 0; m_ < 4; ++m_) { \
      const int r_ = wr + m_ * 16 + fr; \
      af_[m_] = *(const bf16x8*)&(A_)[r_ * 64 + ((cc_ ^ (r_ & 7)) << 3)]; \
    } \
    _Pragma("unroll") \
    for (int n_ = 0; n_ < 4; ++n_) { \
      const int r_ = wc + n_ * 16 + fr; \
      bv_[n_] = *(const bf16x8*)&(B_)[r_ * 64 + ((cc_ ^ (r_ & 7)) << 3)]; \
    } \
    _Pragma("unroll") \
    for (int m_ = 0; m_ < 4; ++m_) \
      _Pragma("unroll") \
      for (int n_ = 0; n_ < 4; ++n_) \
        acc[m_][n_] = __builtin_amdgcn_mfma_f32_16x16x32_bf16(af_[m_], bv_[n_], acc[m_][n_], 0, 0, 0); \
  } \
} while (0)

// ---------------- 4. grouped up-GEMM + bias + GELU + weight scaling ----------------
__global__ __launch_bounds__(256) void up_gemm(const ushort_t* __restrict__ Xbf,
                                               const ushort_t* __restrict__ Wub,
                                               const int* __restrict__ counts,
                                               const int* __restrict__ offs,
                                               const int* __restrict__ rid,
                                               const float* __restrict__ wts,
                                               const float* __restrict__ bu,
                                               const float* __restrict__ sbu,
                                               ushort_t* __restrict__ Aout) {
  const int g = blockIdx.y >> 4;
  const int mt = blockIdx.y & 15;
  const int rows = counts[g];
  if (mt * 128 >= rows) return;
  const int off = offs[g];
  const int n0 = blockIdx.x * 128;

  __shared__ ushort_t lds[4][128 * 64];   // [A0,B0,A1,B1] = 64KB

  const int tid = threadIdx.x;
  const int lane = tid & 63;
  const int wid = tid >> 6;
  const int sr = lane >> 3;
  const int swz = ((lane & 7) ^ sr) << 3;

  const ushort_t* Wg = Wub + (size_t)g * F_DIM * H_DIM;
  const ushort_t* pA[4];
  const ushort_t* pB[4];
#pragma unroll
  for (int i = 0; i < 4; ++i) {
    const int rA = (wid * 4 + i) * 8 + sr;
    int ig = mt * 128 + rA;
    if (ig >= rows) ig = rows - 1;
    pA[i] = Xbf + (size_t)(rid[off + ig] >> 2) * H_DIM + swz;
    pB[i] = Wg + (size_t)(n0 + rA) * H_DIM + swz;
  }

  f32x4 acc[4][4];
#pragma unroll
  for (int m = 0; m < 4; ++m)
#pragma unroll
    for (int n = 0; n < 4; ++n) acc[m][n] = (f32x4){0.f, 0.f, 0.f, 0.f};

  const int wr = (wid >> 1) * 64;
  const int wc = (wid & 1) * 64;
  const int fr = lane & 15;
  const int hi = lane >> 4;

  // 2-phase pipeline over 16 K-tiles
  STAGE_T(lds[0], lds[1], 0);
  VMCNT0_BARRIER;
#pragma unroll 1
  for (int kt = 0; kt < 16; kt += 2) {
    STAGE_T(lds[2], lds[3], (kt + 1) * 64);
    COMPUTE_T(lds[0], lds[1]);
    VMCNT0_BARRIER;
    if (kt + 2 < 16) STAGE_T(lds[0], lds[1], (kt + 2) * 64);
    COMPUTE_T(lds[2], lds[3]);
    VMCNT0_BARRIER;
  }

  const float* bug = (g < E_NUM) ? (bu + (size_t)g * F_DIM) : sbu;
#pragma unroll
  for (int m = 0; m < 4; ++m) {
#pragma unroll
    for (int q = 0; q < 4; ++q) {
      const int r = wr + m * 16 + hi * 4 + q;
      const int ig = mt * 128 + r;
      if (ig < rows) {
        const float wrow = wts[off + ig];
        const size_t rowbase = (size_t)(off + ig) * F_DIM + n0;
#pragma unroll
        for (int n = 0; n < 4; ++n) {
          const int c = wc + n * 16 + fr;
          const float v = acc[m][n][q] + bug[n0 + c];
          Aout[rowbase + c] = f2bf(gelu_fast(v) * wrow);
        }
      }
    }
  }
}

// ---------------- 5. grouped down-GEMM, split-K x2, deterministic bf16 Y scatter ----------------
__global__ __launch_bounds__(256) void down_gemm(const ushort_t* __restrict__ Ain,
                                                 const ushort_t* __restrict__ Wdb,
                                                 const int* __restrict__ counts,
                                                 const int* __restrict__ offs,
                                                 const int* __restrict__ rid,
                                                 ushort_t* __restrict__ Ybf) {
  const int g = blockIdx.y >> 4;
  const int mt = blockIdx.y & 15;
  const int rows = counts[g];
  if (mt * 128 >= rows) return;
  const int off = offs[g];
  const int n0 = blockIdx.x * 128;
  const int kbase = blockIdx.z * 2048;
  ushort_t* Ys = Ybf + (size_t)blockIdx.z * Y_SPLIT_STRIDE;

  __shared__ ushort_t lds[4][128 * 64];   // 64KB

  const int tid = threadIdx.x;
  const int lane = tid & 63;
  const int wid = tid >> 6;
  const int sr = lane >> 3;
  const int swz = ((lane & 7) ^ sr) << 3;

  const ushort_t* Wg = Wdb + (size_t)g * H_DIM * F_DIM;
  const ushort_t* pA[4];
  const ushort_t* pB[4];
#pragma unroll
  for (int i = 0; i < 4; ++i) {
    const int rA = (wid * 4 + i) * 8 + sr;
    pA[i] = Ain + (size_t)(off + mt * 128 + rA) * F_DIM + kbase + swz;
    pB[i] = Wg + (size_t)(n0 + rA) * F_DIM + kbase + swz;
  }

  f32x4 acc[4][4];
#pragma unroll
  for (int m = 0; m < 4; ++m)
#pragma unroll
    for (int n = 0; n < 4; ++n) acc[m][n] = (f32x4){0.f, 0.f, 0.f, 0.f};

  const int wr = (wid >> 1) * 64;
  const int wc = (wid & 1) * 64;
  const int fr = lane & 15;
  const int hi = lane >> 4;

  // 2-phase pipeline over 32 K-tiles
  STAGE_T(lds[0], lds[1], 0);
  VMCNT0_BARRIER;
#pragma unroll 1
  for (int kt = 0; kt < 32; kt += 2) {
    STAGE_T(lds[2], lds[3], (kt + 1) * 64);
    COMPUTE_T(lds[0], lds[1]);
    VMCNT0_BARRIER;
    if (kt + 2 < 32) STAGE_T(lds[0], lds[1], (kt + 2) * 64);
    COMPUTE_T(lds[2], lds[3]);
    VMCNT0_BARRIER;
  }

#pragma unroll
  for (int m = 0; m < 4; ++m) {
#pragma unroll
    for (int q = 0; q < 4; ++q) {
      const int r = wr + m * 16 + hi * 4 + q;
      const int ig = mt * 128 + r;
      if (ig < rows) {
        const int rv = rid[off + ig];
        ushort_t* yrow = Ys + ((size_t)(rv >> 2) * 3 + (rv & 3)) * H_DIM + n0;
#pragma unroll
        for (int n = 0; n < 4; ++n) {
          const int c = wc + n * 16 + fr;
          yrow[c] = f2bf(acc[m][n][q]);
        }
      }
    }
  }
}

// ---------------- 6. combine: 2 splits x 3 slots + bias terms ----------------
__global__ __launch_bounds__(256) void combine_k(const ushort_t* __restrict__ Ybf,
                                                 const int* __restrict__ tt_idx,
                                                 const float* __restrict__ tt_w,
                                                 const float* __restrict__ bd,
                                                 const float* __restrict__ sbd,
                                                 float* __restrict__ out) {
  const int t = blockIdx.x;
  const int h = threadIdx.x * 4;
  const int e0 = tt_idx[2 * t];
  const int e1 = tt_idx[2 * t + 1];
  const float w0 = tt_w[2 * t];
  const float w1 = tt_w[2 * t + 1];
  float s[4] = {0.f, 0.f, 0.f, 0.f};
#pragma unroll
  for (int sp = 0; sp < 2; ++sp) {
#pragma unroll
    for (int sl = 0; sl < 3; ++sl) {
      const ushort_t* yp = Ybf + sp * Y_SPLIT_STRIDE + ((size_t)t * 3 + sl) * H_DIM + h;
      const ushort4 v = *(const ushort4*)yp;
      s[0] += bf2f(v.x); s[1] += bf2f(v.y); s[2] += bf2f(v.z); s[3] += bf2f(v.w);
    }
  }
  const float4 b0 = *(const float4*)(bd + (size_t)e0 * H_DIM + h);
  const float4 b1 = *(const float4*)(bd + (size_t)e1 * H_DIM + h);
  const float4 bs = *(const float4*)(sbd + h);
  float4 o;
  o.x = s[0] + w0 * b0.x + w1 * b1.x + 0.1f * bs.x;
  o.y = s[1] + w0 * b0.y + w1 * b1.y + 0.1f * bs.y;
  o.z = s[2] + w0 * b0.z + w1 * b1.z + 0.1f * bs.z;
  o.w = s[3] + w0 * b0.w + w1 * b1.w + 0.1f * bs.w;
  *(float4*)(out + (size_t)t * H_DIM + h) = o;
}

extern "C" void kernel_launch(void* const* d_in, const int* in_sizes, int n_in,
                              void* d_out, int out_size, void* d_ws, size_t ws_size,
                              hipStream_t stream) {
  (void)in_sizes; (void)n_in; (void)out_size; (void)ws_size;
  const float* x = (const float*)d_in[0];
  const float* gate_w = (const float*)d_in[1];
  const float* gate_b = (const float*)d_in[2];
  const float* Wu = (const float*)d_in[3];
  const float* bu = (const float*)d_in[4];
  const float* Wd = (const float*)d_in[5];
  const float* bd = (const float*)d_in[6];
  const float* sWu = (const float*)d_in[7];
  const float* sbu = (const float*)d_in[8];
  const float* sWd = (const float*)d_in[9];
  const float* sbd = (const float*)d_in[10];
  float* out = (float*)d_out;

  char* ws = (char*)d_ws;
  int* tt_idx = (int*)(ws + OFF_TTI);
  float* tt_w = (float*)(ws + OFF_TTW);
  int* counts = (int*)(ws + OFF_CNT);
  int* offs = (int*)(ws + OFF_OFFS);
  int* rid = (int*)(ws + OFF_RID);
  float* wts = (float*)(ws + OFF_WTS);
  ushort_t* Xbf = (ushort_t*)(ws + OFF_XBF);
  ushort_t* Wub = (ushort_t*)(ws + OFF_WUB);
  ushort_t* Wdb = (ushort_t*)(ws + OFF_WDB);
  ushort_t* A = (ushort_t*)(ws + OFF_A);
  ushort_t* Y = (ushort_t*)(ws + OFF_Y);

  hipLaunchKernelGGL(route_k, dim3(T_TOK / 4), dim3(256), 0, stream,
                     x, gate_w, gate_b, tt_idx, tt_w);
  hipLaunchKernelGGL(build_k, dim3(1), dim3(256), 0, stream,
                     tt_idx, tt_w, counts, offs, rid, wts);
  hipLaunchKernelGGL(convert_k, dim3(4096), dim3(256), 0, stream,
                     Wu, sWu, Wd, sWd, x, Wub, Wdb, Xbf);
  hipLaunchKernelGGL(up_gemm, dim3(F_DIM / 128, NG * 16), dim3(256), 0, stream,
                     Xbf, Wub, counts, offs, rid, wts, bu, sbu, A);
  hipLaunchKernelGGL(down_gemm, dim3(H_DIM / 128, NG * 16, 2), dim3(256), 0, stream,
                     A, Wdb, counts, offs, rid, Y);
  hipLaunchKernelGGL(combine_k, dim3(T_TOK), dim3(256), 0, stream,
                     Y, tt_idx, tt_w, bd, sbd, out);
}